// Round 12
// baseline (151.666 us; speedup 1.0000x reference)
//
#include <hip/hip_runtime.h>
#include <hip/hip_bf16.h>
#include <cstdint>

// ---------------------------------------------------------------------------
// GAT forward, N=4096, F=512, D=64, H=8, O=128, fp32 in/out.
// Identity: exp(lrelu(u)) = max(exp(u), exp(0.2u)); u = s1_i+s2_j rank-1;
// softmax row-scale invariance => p'_ij = max(E2_j, g_i*F2_j), g=exp(-0.8 s1).
// Round-12 = Round-9 (proven: 141us, absmax 9.8e-4) with ONE change:
//   masking via byte-mask AND: adjacency pre-expanded to 0xFF/0x00 bytes
//   (mask8[j>>5][i][j&31]); agg converts p (f32 math, unchanged) to bf16
//   then ANDs packed pairs with v_perm-expanded halfword masks -> replaces
//   8 bit-test+cndmask chains with 4 perm + 4 and per 8 elements.
// Diagnostic: if this FAILS, the mask path was R11's residual bug.
// ---------------------------------------------------------------------------

using bf16_t = __bf16;
using bf16x4 = __attribute__((ext_vector_type(4))) __bf16;
using bf16x8 = __attribute__((ext_vector_type(8))) __bf16;
using f32x4  = __attribute__((ext_vector_type(4))) float;
using u32x4  = __attribute__((ext_vector_type(4))) uint32_t;

#define LOG2E 1.44269504f
constexpr int NN = 4096;

// byte (0xFF/0x00) -> halfword AND-mask expansion
__device__ inline uint32_t expand01(uint32_t b) {
#if __has_builtin(__builtin_amdgcn_perm)
    return __builtin_amdgcn_perm(0u, b, 0x01010000u);
#else
    return ((b & 0xFFu) * 0x101u) | ((((b >> 8) & 0xFFu) * 0x101u) << 16);
#endif
}
__device__ inline uint32_t expand23(uint32_t b) {
#if __has_builtin(__builtin_amdgcn_perm)
    return __builtin_amdgcn_perm(0u, b, 0x03030202u);
#else
    return (((b >> 16) & 0xFFu) * 0x101u) | ((((b >> 24) & 0xFFu) * 0x101u) << 16);
#endif
}

// ---- adjacency -> byte mask, j-tiled: mask8[j>>5][i][j&31] = adj ? 0xFF : 0
__global__ __launch_bounds__(256) void expand_k(const int* __restrict__ adj,
                                                uint8_t* __restrict__ mask8) {
    const int total8 = NN * NN / 8;
    int stride = gridDim.x * blockDim.x;
    for (int t = blockIdx.x * blockDim.x + threadIdx.x; t < total8; t += stride) {
        size_t d = (size_t)t * 8;
        int jc = (int)(d >> 17);
        int rem = (int)(d & 131071);
        int i = rem >> 5, j0 = rem & 31;
        const int* ap = adj + (size_t)i * NN + jc * 32 + j0;
        int4 a0 = *(const int4*)ap;
        int4 a1 = *(const int4*)(ap + 4);
        uint32_t w0 = (a0.x > 0 ? 0xFFu : 0u) | ((a0.y > 0 ? 0xFFu : 0u) << 8) |
                      ((a0.z > 0 ? 0xFFu : 0u) << 16) | ((a0.w > 0 ? 0xFFu : 0u) << 24);
        uint32_t w1 = (a1.x > 0 ? 0xFFu : 0u) | ((a1.y > 0 ? 0xFFu : 0u) << 8) |
                      ((a1.z > 0 ? 0xFFu : 0u) << 16) | ((a1.w > 0 ? 0xFFu : 0u) << 24);
        uint2 w; w.x = w0; w.y = w1;
        *(uint2*)(mask8 + d) = w;
    }
}

// ---- prep: x->bf16, W_heads [H][F][D] -> WT1[(h*64+d)][F], W_out -> WoutT[o][512]
__global__ __launch_bounds__(256) void prep_k(const float* __restrict__ x,
                                              const float* __restrict__ Wh,
                                              const float* __restrict__ Wo,
                                              bf16_t* __restrict__ xb,
                                              bf16_t* __restrict__ WT1,
                                              bf16_t* __restrict__ WoutT) {
    const int NX = NN * 512, NW1 = 512 * 512, NW2 = 128 * 512;
    int stride = gridDim.x * blockDim.x;
    for (int t = blockIdx.x * blockDim.x + threadIdx.x; t < NX + NW1 + NW2; t += stride) {
        if (t < NX) {
            xb[t] = (bf16_t)x[t];
        } else if (t < NX + NW1) {
            int u = t - NX; int hd = u >> 9, f = u & 511; int h = hd >> 6, d = hd & 63;
            WT1[u] = (bf16_t)Wh[(h << 15) + (f << 6) + d];
        } else {
            int u = t - NX - NW1; int o = u >> 9, cc = u & 511;
            WoutT[u] = (bf16_t)Wo[cc * 128 + o];
        }
    }
}

// ---- bf16 MFMA GEMM, 4 waves/block, wave = 16 rows x 64 cols.
// CS: epilogue writes VTt (j-tiled: [i>>5][col][i&31]) + g/E2/F2 (cb=head*64)
// WC: writes fp32 partial C slice (split-K via blockIdx.z)
template<int CS, int WC>
__global__ __launch_bounds__(256) void gemm_k(const bf16_t* __restrict__ A,
                                              const bf16_t* __restrict__ BT,
                                              bf16_t* __restrict__ VTt,
                                              float* __restrict__ Cp,
                                              const float* __restrict__ a1,
                                              const float* __restrict__ a2,
                                              float* __restrict__ g1,
                                              float* __restrict__ E2,
                                              float* __restrict__ F2,
                                              int K, int NC, int kslice, int NCOLS) {
    const int wave = threadIdx.x >> 6, lane = threadIdx.x & 63;
    const int lr = lane & 15, kg = lane >> 4;
    const int rowb = (blockIdx.x * 4 + wave) * 16, cb = blockIdx.y * 64, kz = blockIdx.z;
    f32x4 acc[4];
#pragma unroll
    for (int dt = 0; dt < 4; ++dt) acc[dt] = 0.0f;
    const bf16_t* Ap = A + (size_t)(rowb + lr) * K;
    const int k0beg = kz * kslice, k0end = k0beg + kslice;
    for (int k0 = k0beg; k0 < k0end; k0 += 32) {
        bf16x8 af = *(const bf16x8*)(Ap + k0 + kg * 8);
#pragma unroll
        for (int dt = 0; dt < 4; ++dt) {
            bf16x8 bfr = *(const bf16x8*)(BT + (size_t)(cb + dt * 16 + lr) * K + k0 + kg * 8);
            acc[dt] = __builtin_amdgcn_mfma_f32_16x16x32_bf16(af, bfr, acc[dt], 0, 0, 0);
        }
    }
    if (WC) {
#pragma unroll
        for (int dt = 0; dt < 4; ++dt)
#pragma unroll
            for (int r = 0; r < 4; ++r)
                Cp[((size_t)kz * NN + rowb + kg * 4 + r) * NC + cb + dt * 16 + lr] = acc[dt][r];
    }
    if (CS) {
        const int i0 = rowb + kg * 4;
        const size_t tbase = (size_t)(i0 >> 5) * NCOLS * 32 + (i0 & 31);
#pragma unroll
        for (int dt = 0; dt < 4; ++dt) {
            bf16x4 v;
#pragma unroll
            for (int r = 0; r < 4; ++r) v[r] = (bf16_t)acc[dt][r];
            *(bf16x4*)(VTt + tbase + (size_t)(cb + dt * 16 + lr) * 32) = v;
        }
        float a1v[4], a2v[4];
#pragma unroll
        for (int dt = 0; dt < 4; ++dt) {
            a1v[dt] = a1[cb + dt * 16 + lr];
            a2v[dt] = a2[cb + dt * 16 + lr];
        }
#pragma unroll
        for (int r = 0; r < 4; ++r) {
            float d1 = 0.f, d2 = 0.f;
#pragma unroll
            for (int dt = 0; dt < 4; ++dt) { d1 += acc[dt][r] * a1v[dt]; d2 += acc[dt][r] * a2v[dt]; }
#pragma unroll
            for (int o = 1; o < 16; o <<= 1) { d1 += __shfl_xor(d1, o); d2 += __shfl_xor(d2, o); }
            if (lr == 0) {
                size_t row = (size_t)blockIdx.y * NN + rowb + kg * 4 + r;
                g1[row] = exp2f(-0.8f * LOG2E * d1);
                E2[row] = exp2f(LOG2E * d2);
                F2[row] = exp2f(0.2f * LOG2E * d2);
            }
        }
    }
}

// ---- fused attention-aggregate (R9 structure, byte-mask AND).
// grid = (CG*JZG, 64); x -> (c = x/JZG, jzgrp = x%JZG); y = rowtile.
// 4 waves/block; wave w owns jz = jzgrp*4 + w; wave = 64 rows x 64 cols.
// p'_ij = adj ? max(E2_j, g_i*F2_j) : 0 -- f32 math, bf16 cvt, AND mask.
// Z row-sums via extra MFMA against a ones-column B-fragment.
template<int JZG>
__global__ __launch_bounds__(256) void gat_agg_k(const float* __restrict__ g1,
                                                 const float* __restrict__ E2,
                                                 const float* __restrict__ F2, int shead,
                                                 const uint8_t* __restrict__ mask8,
                                                 const bf16_t* __restrict__ VTt,
                                                 bf16_t* __restrict__ Hpart,
                                                 float* __restrict__ zpart,
                                                 int CT, int JR, int ZC, int TS) {
    const int wave = threadIdx.x >> 6, lane = threadIdx.x & 63;
    const int lr = lane & 15, kg = lane >> 4;
    const int c = blockIdx.x / JZG, jzg = blockIdx.x % JZG;
    const int rowb = blockIdx.y * 64;
    const int jz = jzg * 4 + wave;
    const int cb = c * 64;
    const float* gp  = g1 + (size_t)shead * c;
    const float* E2p = E2 + (size_t)shead * c;
    const float* F2p = F2 + (size_t)shead * c;
    const int steps = JR >> 5, jb0 = jz * JR;

    f32x4 acc[4][4], accz[4];
#pragma unroll
    for (int rt = 0; rt < 4; ++rt) {
        accz[rt] = 0.0f;
#pragma unroll
        for (int dt = 0; dt < 4; ++dt) acc[rt][dt] = 0.0f;
    }
    float gv[4];
#pragma unroll
    for (int rt = 0; rt < 4; ++rt) gv[rt] = gp[rowb + rt * 16 + lr];
    bf16x8 ones;
#pragma unroll
    for (int e = 0; e < 8; ++e) ones[e] = (bf16_t)(lr == 0 ? 1.0f : 0.0f);

    auto LOAD = [&](int jb, bf16x8* bfr, f32x4& e2a, f32x4& e2b, f32x4& f2a, f32x4& f2b,
                    uint2* mk) {
        const int jk = jb + kg * 8;
        const int jc = jb >> 5;
        e2a = *(const f32x4*)(E2p + jk);
        e2b = *(const f32x4*)(E2p + jk + 4);
        f2a = *(const f32x4*)(F2p + jk);
        f2b = *(const f32x4*)(F2p + jk + 4);
        const bf16_t* vb = VTt + (size_t)jc * TS + kg * 8;
#pragma unroll
        for (int dt = 0; dt < 4; ++dt)
            bfr[dt] = *(const bf16x8*)(vb + (size_t)(cb + dt * 16 + lr) * 32);
        const uint8_t* mp = mask8 + (size_t)jc * (NN * 32) + (size_t)(rowb + lr) * 32 + kg * 8;
#pragma unroll
        for (int rt = 0; rt < 4; ++rt)
            mk[rt] = *(const uint2*)(mp + rt * 512);
    };
    auto COMP = [&](const bf16x8* bfr, f32x4 e2a, f32x4 e2b, f32x4 f2a, f32x4 f2b,
                    const uint2* mk) {
#pragma unroll
        for (int rt = 0; rt < 4; ++rt) {
            bf16x8 raw;
#pragma unroll
            for (int e = 0; e < 8; ++e) {
                float e2 = (e < 4) ? e2a[e] : e2b[e - 4];
                float f2 = (e < 4) ? f2a[e] : f2b[e - 4];
                raw[e] = (bf16_t)fmaxf(e2, gv[rt] * f2);
            }
            u32x4 ru = __builtin_bit_cast(u32x4, raw);
#pragma unroll
            for (int p = 0; p < 4; ++p) {
                uint32_t mb = (p < 2) ? mk[rt].x : mk[rt].y;
                ru[p] &= (p & 1) ? expand23(mb) : expand01(mb);
            }
            bf16x8 af = __builtin_bit_cast(bf16x8, ru);
#pragma unroll
            for (int dt = 0; dt < 4; ++dt)
                acc[rt][dt] = __builtin_amdgcn_mfma_f32_16x16x32_bf16(af, bfr[dt], acc[rt][dt], 0, 0, 0);
            accz[rt] = __builtin_amdgcn_mfma_f32_16x16x32_bf16(af, ones, accz[rt], 0, 0, 0);
        }
    };

    bf16x8 bA[4], bB[4];
    f32x4 eaA, ebA, faA, fbA, eaB, ebB, faB, fbB;
    uint2 mA[4], mB[4];
    LOAD(jb0, bA, eaA, ebA, faA, fbA, mA);
    for (int js = 0; js < steps - 2; js += 2) {
        LOAD(jb0 + (js + 1) * 32, bB, eaB, ebB, faB, fbB, mB);
        COMP(bA, eaA, ebA, faA, fbA, mA);
        LOAD(jb0 + (js + 2) * 32, bA, eaA, ebA, faA, fbA, mA);
        COMP(bB, eaB, ebB, faB, fbB, mB);
    }
    LOAD(jb0 + (steps - 1) * 32, bB, eaB, ebB, faB, fbB, mB);
    COMP(bA, eaA, ebA, faA, fbA, mA);
    COMP(bB, eaB, ebB, faB, fbB, mB);

    bf16_t* Hp = Hpart + (size_t)jz * NN * CT;
#pragma unroll
    for (int rt = 0; rt < 4; ++rt) {
#pragma unroll
        for (int dt = 0; dt < 4; ++dt)
#pragma unroll
            for (int r = 0; r < 4; ++r)
                Hp[(size_t)(rowb + rt * 16 + kg * 4 + r) * CT + cb + dt * 16 + lr] = (bf16_t)acc[rt][dt][r];
    }
    if (lr == 0 && (ZC > 1 || c == 0)) {
        int zi = jz * ZC + (ZC > 1 ? c : 0);
#pragma unroll
        for (int rt = 0; rt < 4; ++rt)
#pragma unroll
            for (int r = 0; r < 4; ++r)
                zpart[(size_t)zi * NN + rowb + rt * 16 + kg * 4 + r] = accz[rt][r];
    }
}

// ---- finalize layer 1: hcatb = bf16(ELU(sum H / sum Z)), 8 cols/thread
__global__ __launch_bounds__(256) void fin1_k(const bf16_t* __restrict__ Hpart,
                                              const float* __restrict__ zpart,
                                              bf16_t* __restrict__ hcatb) {
    int idx = blockIdx.x * 256 + threadIdx.x;   // < N*64
    int i = idx >> 6, col0 = (idx & 63) << 3, h = col0 >> 6;
    float Z = 0.f;
#pragma unroll
    for (int jz = 0; jz < 8; ++jz) Z += zpart[(size_t)(jz * 8 + h) * NN + i];
    float hs[8];
#pragma unroll
    for (int e = 0; e < 8; ++e) hs[e] = 0.f;
#pragma unroll
    for (int jz = 0; jz < 8; ++jz) {
        bf16x8 v = *(const bf16x8*)(Hpart + ((size_t)jz * NN + i) * 512 + col0);
#pragma unroll
        for (int e = 0; e < 8; ++e) hs[e] += (float)v[e];
    }
    float invZ = 1.0f / Z;
    bf16x8 o;
#pragma unroll
    for (int e = 0; e < 8; ++e) {
        float v = hs[e] * invZ;
        o[e] = (bf16_t)(v > 0.f ? v : expm1f(v));
    }
    *(bf16x8*)(hcatb + (size_t)i * 512 + col0) = o;
}

// ---- combine split-K gemm2 slices: VT2 (j-tiled) + g/E2/F2. block=128thr=1 row.
__global__ __launch_bounds__(128) void comb2_k(const float* __restrict__ Cp,
                                               const float* __restrict__ a1o,
                                               const float* __restrict__ a2o,
                                               bf16_t* __restrict__ VT2t,
                                               float* __restrict__ g1o,
                                               float* __restrict__ E2o,
                                               float* __restrict__ F2o) {
    int r = blockIdx.x, t = threadIdx.x;
    float w = 0.f;
#pragma unroll
    for (int z = 0; z < 4; ++z) w += Cp[((size_t)z * NN + r) * 128 + t];
    VT2t[(size_t)(r >> 5) * (128 * 32) + t * 32 + (r & 31)] = (bf16_t)w;
    float d1 = w * a1o[t], d2 = w * a2o[t];
#pragma unroll
    for (int o = 1; o < 64; o <<= 1) { d1 += __shfl_xor(d1, o); d2 += __shfl_xor(d2, o); }
    __shared__ float red[4];
    if ((t & 63) == 0) { red[(t >> 6) * 2 + 0] = d1; red[(t >> 6) * 2 + 1] = d2; }
    __syncthreads();
    if (t == 0) {
        float s1 = red[0] + red[2], s2 = red[1] + red[3];
        g1o[r] = exp2f(-0.8f * LOG2E * s1);
        E2o[r] = exp2f(LOG2E * s2);
        F2o[r] = exp2f(0.2f * LOG2E * s2);
    }
}

// ---- finalize layer 2: out fp32 = sum H / sum Z, 8 cols/thread
__global__ __launch_bounds__(256) void fin2_k(const bf16_t* __restrict__ Hpart,
                                              const float* __restrict__ zpart,
                                              float* __restrict__ out) {
    int idx = blockIdx.x * 256 + threadIdx.x;   // < N*16
    int i = idx >> 4, col0 = (idx & 15) << 3;
    float Z = 0.f;
#pragma unroll
    for (int jz = 0; jz < 16; ++jz) Z += zpart[(size_t)jz * NN + i];
    float hs[8];
#pragma unroll
    for (int e = 0; e < 8; ++e) hs[e] = 0.f;
#pragma unroll
    for (int jz = 0; jz < 16; ++jz) {
        bf16x8 v = *(const bf16x8*)(Hpart + ((size_t)jz * NN + i) * 128 + col0);
#pragma unroll
        for (int e = 0; e < 8; ++e) hs[e] += (float)v[e];
    }
    float invZ = 1.0f / Z;
    f32x4 o0, o1;
#pragma unroll
    for (int e = 0; e < 4; ++e) { o0[e] = hs[e] * invZ; o1[e] = hs[e + 4] * invZ; }
    *(f32x4*)(out + (size_t)i * 128 + col0) = o0;
    *(f32x4*)(out + (size_t)i * 128 + col0 + 4) = o1;
}

extern "C" void kernel_launch(void* const* d_in, const int* in_sizes, int n_in,
                              void* d_out, int out_size, void* d_ws, size_t ws_size,
                              hipStream_t stream) {
    const int N = 4096;
    const float* x       = (const float*)d_in[0];
    const int*   adj     = (const int*)d_in[1];
    const float* W_heads = (const float*)d_in[2];
    const float* a1h     = (const float*)d_in[3];
    const float* a2h     = (const float*)d_in[4];
    const float* W_out   = (const float*)d_in[5];
    const float* a1o     = (const float*)d_in[6];
    const float* a2o     = (const float*)d_in[7];
    (void)in_sizes; (void)n_in; (void)out_size; (void)ws_size;

    size_t off = 0;
    auto alloc = [&](size_t bytes) { size_t o = off; off = (off + bytes + 255) & ~(size_t)255; return o; };
    char* ws = (char*)d_ws;
    uint8_t* mask8  = (uint8_t*)(ws + alloc((size_t)N * N));             // 16 MB
    bf16_t* VT1t    = (bf16_t*)(ws + alloc((size_t)512 * N * 2));        // 4 MB (j-tiled)
    bf16_t* hcatb   = (bf16_t*)(ws + alloc((size_t)N * 512 * 2));        // 4 MB
    bf16_t* WoutT   = (bf16_t*)(ws + alloc((size_t)128 * 512 * 2));      // 128 KB
    float*  g1h     = (float*)(ws + alloc((size_t)8 * N * 4));
    float*  E2h     = (float*)(ws + alloc((size_t)8 * N * 4));
    float*  F2h     = (float*)(ws + alloc((size_t)8 * N * 4));
    float*  g1o     = (float*)(ws + alloc((size_t)N * 4));
    float*  E2o     = (float*)(ws + alloc((size_t)N * 4));
    float*  F2o     = (float*)(ws + alloc((size_t)N * 4));
    bf16_t* VT2t    = (bf16_t*)(ws + alloc((size_t)128 * N * 2));        // 1 MB (j-tiled)
    float*  zpart   = (float*)(ws + alloc((size_t)64 * N * 4));          // 1 MB
    bf16_t* Hpart   = (bf16_t*)(ws + alloc((size_t)32 * 1024 * 1024));   // 32 MB
    // aliases into the Hpart region (temporally disjoint):
    bf16_t* xb    = (bf16_t*)Hpart;                       // dead after gemm1
    bf16_t* WT1   = (bf16_t*)((char*)Hpart + (9 << 20));  // dead after gemm1
    float*  Cpart = (float*)Hpart;                        // gemm2..comb2 only

    // 1. adjacency byte-mask (j-tiled)
    hipLaunchKernelGGL(expand_k, dim3(2048), dim3(256), 0, stream, adj, mask8);
    // 2. prep conversions/transposes
    hipLaunchKernelGGL(prep_k, dim3(1024), dim3(256), 0, stream, x, W_heads, W_out, xb, WT1, WoutT);
    // 3. gemm1: VT1 tiled + g/E2/F2 per head  (4-wave blocks)
    hipLaunchKernelGGL((gemm_k<1, 0>), dim3(64, 8, 1), dim3(256), 0, stream,
                       xb, WT1, VT1t, (float*)nullptr, a1h, a2h, g1h, E2h, F2h, 512, 512, 512, 512);
    // 4. layer-1 aggregate: grid x=(head,jzgrp)=16, y=rowtile=64; jz = jzgrp*4+wave
    hipLaunchKernelGGL((gat_agg_k<2>), dim3(16, 64, 1), dim3(256), 0, stream,
                       g1h, E2h, F2h, N, mask8, VT1t, Hpart, zpart, 512, 512, 8, 512 * 32);
    // 5. finalize 1 -> hcatb
    hipLaunchKernelGGL(fin1_k, dim3(1024), dim3(256), 0, stream, Hpart, zpart, hcatb);
    // 6. gemm2 split-K=4 -> Cpart  (4-wave blocks)
    hipLaunchKernelGGL((gemm_k<0, 1>), dim3(64, 2, 4), dim3(256), 0, stream,
                       hcatb, WoutT, (bf16_t*)nullptr, Cpart,
                       (const float*)nullptr, (const float*)nullptr,
                       (float*)nullptr, (float*)nullptr, (float*)nullptr, 512, 128, 128, 128);
    // 7. combine -> VT2 tiled, g1o/E2o/F2o
    hipLaunchKernelGGL(comb2_k, dim3(4096), dim3(128), 0, stream, Cpart, a1o, a2o, VT2t, g1o, E2o, F2o);
    // 8. layer-2 aggregate: grid x=(c,jzgrp)=8, y=rowtile=64; jz = jzgrp*4+wave
    hipLaunchKernelGGL((gat_agg_k<4>), dim3(8, 64, 1), dim3(256), 0, stream,
                       g1o, E2o, F2o, 0, mask8, VT2t, Hpart, zpart, 128, 256, 1, 128 * 32);
    // 9. finalize 2 -> out
    hipLaunchKernelGGL(fin2_k, dim3(256), dim3(256), 0, stream, Hpart, zpart, (float*)d_out);
}

// Round 13
// 139.572 us; speedup vs baseline: 1.0866x; 1.0866x over previous
//
#include <hip/hip_runtime.h>
#include <hip/hip_bf16.h>
#include <cstdint>

// ---------------------------------------------------------------------------
// GAT forward, N=4096, F=512, D=64, H=8, O=128, fp32 in/out.
// Identity: exp(lrelu(u)) = max(exp(u), exp(0.2u)); u = s1_i+s2_j rank-1;
// softmax row-scale invariance => p'_ij = max(E2_j, g_i*F2_j), g=exp(-0.8 s1).
// Round-13 = Round-9 (proven 141us) + K-tiled bf16 GEMM-1 inputs:
//   xbt[kc][4096][32], WT1t[kc][512][32] -> gemm1 fragment loads are dense
//   1KB bursts (8 full lines/inst) instead of 16 sparse half-lines,
//   the same line-request fix that took agg 78->49. gemm2 stays row-major.
// Agg (bitsT + cndmask masking), fins, comb2: byte-identical to R9.
// ---------------------------------------------------------------------------

using bf16_t = __bf16;
using bf16x4 = __attribute__((ext_vector_type(4))) __bf16;
using bf16x8 = __attribute__((ext_vector_type(8))) __bf16;
using f32x4  = __attribute__((ext_vector_type(4))) float;

#define LOG2E 1.44269504f
constexpr int NN = 4096;

// ---- pack adjacency into TRANSPOSED bitmask: bitsT[(j>>5)*N + i], bit j&31
__global__ __launch_bounds__(256) void pack_bits_k(const int* __restrict__ adj,
                                                   uint32_t* __restrict__ bitsT, int total) {
    int stride = gridDim.x * blockDim.x;
    for (int idx = blockIdx.x * blockDim.x + threadIdx.x; idx < total; idx += stride) {
        unsigned long long m = __ballot(adj[idx] > 0);
        int l = threadIdx.x & 63;
        int i = idx >> 12, j = idx & 4095;
        if (l == 0)        bitsT[(size_t)(j >> 5) * NN + i] = (uint32_t)m;
        else if (l == 32)  bitsT[(size_t)(j >> 5) * NN + i] = (uint32_t)(m >> 32);
    }
}

// ---- prep: x -> xbt (K-tiled bf16 [kc][4096][32]),
//            W_heads -> WT1t ([kc][512][32]), W_out -> WoutT[o][512] row-major
__global__ __launch_bounds__(256) void prep_k(const float* __restrict__ x,
                                              const float* __restrict__ Wh,
                                              const float* __restrict__ Wo,
                                              bf16_t* __restrict__ xbt,
                                              bf16_t* __restrict__ WT1t,
                                              bf16_t* __restrict__ WoutT) {
    const int NXT = NN * 512 / 8;        // 262144 groups of 8
    const int NWT = 512 * 512 / 8;       // 32768 groups of 8
    const int NW2 = 128 * 512;           // 65536 scalar
    int stride = gridDim.x * blockDim.x;
    for (int t = blockIdx.x * blockDim.x + threadIdx.x; t < NXT + NWT + NW2; t += stride) {
        if (t < NXT) {
            size_t d = (size_t)t * 8;
            int kc = (int)(d >> 17);               // / (4096*32)
            int rem = (int)(d & 131071);
            int i = rem >> 5, k0 = rem & 31;
            const float* sp = x + (size_t)i * 512 + kc * 32 + k0;
            f32x4 s0 = *(const f32x4*)sp;
            f32x4 s1 = *(const f32x4*)(sp + 4);
            bf16x8 o;
#pragma unroll
            for (int e = 0; e < 4; ++e) { o[e] = (bf16_t)s0[e]; o[4 + e] = (bf16_t)s1[e]; }
            *(bf16x8*)(xbt + d) = o;
        } else if (t < NXT + NWT) {
            size_t d = (size_t)(t - NXT) * 8;
            int kc = (int)(d >> 14);               // / (512*32)
            int rem = (int)(d & 16383);
            int col = rem >> 5, k0 = rem & 31;
            int h = col >> 6, dd = col & 63;
            bf16x8 o;
#pragma unroll
            for (int e = 0; e < 8; ++e)
                o[e] = (bf16_t)Wh[(size_t)(h << 15) + (size_t)(kc * 32 + k0 + e) * 64 + dd];
            *(bf16x8*)(WT1t + d) = o;
        } else {
            int u = t - NXT - NWT;                 // < 128*512
            int o2 = u >> 9, cc = u & 511;
            WoutT[u] = (bf16_t)Wo[cc * 128 + o2];
        }
    }
}

// ---- bf16 MFMA GEMM, 4 waves/block, wave = 16 rows x 64 cols.
// TILED=1: A/B read from K-tiled [kc][row|col][32] layouts (dense bursts).
// TILED=0: A row-major [row][K], BT row-major [col][K] (R9 path, gemm2).
// CS: epilogue writes VTt (j-tiled: [i>>5][col][i&31]) + g/E2/F2 (cb=head*64)
// WC: writes fp32 partial C slice (split-K via blockIdx.z)
template<int CS, int WC, int TILED>
__global__ __launch_bounds__(256) void gemm_k(const bf16_t* __restrict__ A,
                                              const bf16_t* __restrict__ BT,
                                              bf16_t* __restrict__ VTt,
                                              float* __restrict__ Cp,
                                              const float* __restrict__ a1,
                                              const float* __restrict__ a2,
                                              float* __restrict__ g1,
                                              float* __restrict__ E2,
                                              float* __restrict__ F2,
                                              int K, int NC, int kslice, int NCOLS) {
    const int wave = threadIdx.x >> 6, lane = threadIdx.x & 63;
    const int lr = lane & 15, kg = lane >> 4;
    const int rowb = (blockIdx.x * 4 + wave) * 16, cb = blockIdx.y * 64, kz = blockIdx.z;
    f32x4 acc[4];
#pragma unroll
    for (int dt = 0; dt < 4; ++dt) acc[dt] = 0.0f;
    const int k0beg = kz * kslice, k0end = k0beg + kslice;
    for (int k0 = k0beg; k0 < k0end; k0 += 32) {
        bf16x8 af;
        if (TILED) {
            const int kc = k0 >> 5;
            af = *(const bf16x8*)(A + (size_t)kc * (NN * 32) + (size_t)(rowb + lr) * 32 + kg * 8);
        } else {
            af = *(const bf16x8*)(A + (size_t)(rowb + lr) * K + k0 + kg * 8);
        }
#pragma unroll
        for (int dt = 0; dt < 4; ++dt) {
            bf16x8 bfr;
            if (TILED) {
                const int kc = k0 >> 5;
                bfr = *(const bf16x8*)(BT + (size_t)kc * (NC * 32) +
                                       (size_t)(cb + dt * 16 + lr) * 32 + kg * 8);
            } else {
                bfr = *(const bf16x8*)(BT + (size_t)(cb + dt * 16 + lr) * K + k0 + kg * 8);
            }
            acc[dt] = __builtin_amdgcn_mfma_f32_16x16x32_bf16(af, bfr, acc[dt], 0, 0, 0);
        }
    }
    if (WC) {
#pragma unroll
        for (int dt = 0; dt < 4; ++dt)
#pragma unroll
            for (int r = 0; r < 4; ++r)
                Cp[((size_t)kz * NN + rowb + kg * 4 + r) * NC + cb + dt * 16 + lr] = acc[dt][r];
    }
    if (CS) {
        const int i0 = rowb + kg * 4;
        const size_t tbase = (size_t)(i0 >> 5) * NCOLS * 32 + (i0 & 31);
#pragma unroll
        for (int dt = 0; dt < 4; ++dt) {
            bf16x4 v;
#pragma unroll
            for (int r = 0; r < 4; ++r) v[r] = (bf16_t)acc[dt][r];
            *(bf16x4*)(VTt + tbase + (size_t)(cb + dt * 16 + lr) * 32) = v;
        }
        float a1v[4], a2v[4];
#pragma unroll
        for (int dt = 0; dt < 4; ++dt) {
            a1v[dt] = a1[cb + dt * 16 + lr];
            a2v[dt] = a2[cb + dt * 16 + lr];
        }
#pragma unroll
        for (int r = 0; r < 4; ++r) {
            float d1 = 0.f, d2 = 0.f;
#pragma unroll
            for (int dt = 0; dt < 4; ++dt) { d1 += acc[dt][r] * a1v[dt]; d2 += acc[dt][r] * a2v[dt]; }
#pragma unroll
            for (int o = 1; o < 16; o <<= 1) { d1 += __shfl_xor(d1, o); d2 += __shfl_xor(d2, o); }
            if (lr == 0) {
                size_t row = (size_t)blockIdx.y * NN + rowb + kg * 4 + r;
                g1[row] = exp2f(-0.8f * LOG2E * d1);
                E2[row] = exp2f(LOG2E * d2);
                F2[row] = exp2f(0.2f * LOG2E * d2);
            }
        }
    }
}

// ---- fused attention-aggregate (R9: tiled-VT + transposed-bits loads).
// grid = (CG*JZG, 64); x -> (c = x/JZG, jzgrp = x%JZG); y = rowtile.
// 4 waves/block; wave w owns jz = jzgrp*4 + w; wave = 64 rows x 64 cols.
// p'_ij = adj ? max(E2_j, g_i*F2_j) : 0. Register double-buffer (A/B sets).
// Z row-sums via extra MFMA against a ones-column B-fragment.
template<int JZG>
__global__ __launch_bounds__(256) void gat_agg_k(const float* __restrict__ g1,
                                                 const float* __restrict__ E2,
                                                 const float* __restrict__ F2, int shead,
                                                 const uint32_t* __restrict__ bitsT,
                                                 const bf16_t* __restrict__ VTt,
                                                 bf16_t* __restrict__ Hpart,
                                                 float* __restrict__ zpart,
                                                 int CT, int JR, int ZC, int TS) {
    const int wave = threadIdx.x >> 6, lane = threadIdx.x & 63;
    const int lr = lane & 15, kg = lane >> 4;
    const int c = blockIdx.x / JZG, jzg = blockIdx.x % JZG;
    const int rowb = blockIdx.y * 64;
    const int jz = jzg * 4 + wave;
    const int cb = c * 64;
    const float* gp  = g1 + (size_t)shead * c;
    const float* E2p = E2 + (size_t)shead * c;
    const float* F2p = F2 + (size_t)shead * c;
    const int steps = JR >> 5, jb0 = jz * JR;

    f32x4 acc[4][4], accz[4];
#pragma unroll
    for (int rt = 0; rt < 4; ++rt) {
        accz[rt] = 0.0f;
#pragma unroll
        for (int dt = 0; dt < 4; ++dt) acc[rt][dt] = 0.0f;
    }
    float gv[4];
#pragma unroll
    for (int rt = 0; rt < 4; ++rt) gv[rt] = gp[rowb + rt * 16 + lr];
    bf16x8 ones;
#pragma unroll
    for (int e = 0; e < 8; ++e) ones[e] = (bf16_t)(lr == 0 ? 1.0f : 0.0f);

    auto LOAD = [&](int jb, bf16x8* bfr, f32x4& e2a, f32x4& e2b, f32x4& f2a, f32x4& f2b,
                    uint32_t* bw) {
        const int jk = jb + kg * 8;
        const int jc = jb >> 5;
        e2a = *(const f32x4*)(E2p + jk);
        e2b = *(const f32x4*)(E2p + jk + 4);
        f2a = *(const f32x4*)(F2p + jk);
        f2b = *(const f32x4*)(F2p + jk + 4);
        const bf16_t* vb = VTt + (size_t)jc * TS + kg * 8;
#pragma unroll
        for (int dt = 0; dt < 4; ++dt)
            bfr[dt] = *(const bf16x8*)(vb + (size_t)(cb + dt * 16 + lr) * 32);
        const uint32_t* bb = bitsT + (size_t)jc * NN + rowb;
#pragma unroll
        for (int rt = 0; rt < 4; ++rt)
            bw[rt] = bb[rt * 16 + lr];
    };
    auto COMP = [&](const bf16x8* bfr, f32x4 e2a, f32x4 e2b, f32x4 f2a, f32x4 f2b,
                    const uint32_t* bw) {
#pragma unroll
        for (int rt = 0; rt < 4; ++rt) {
            uint32_t mb = (bw[rt] >> (kg * 8)) & 0xffu;
            bf16x8 af;
#pragma unroll
            for (int e = 0; e < 8; ++e) {
                float e2 = (e < 4) ? e2a[e] : e2b[e - 4];
                float f2 = (e < 4) ? f2a[e] : f2b[e - 4];
                float p = fmaxf(e2, gv[rt] * f2);
                p = (mb & (1u << e)) ? p : 0.0f;
                af[e] = (bf16_t)p;
            }
#pragma unroll
            for (int dt = 0; dt < 4; ++dt)
                acc[rt][dt] = __builtin_amdgcn_mfma_f32_16x16x32_bf16(af, bfr[dt], acc[rt][dt], 0, 0, 0);
            accz[rt] = __builtin_amdgcn_mfma_f32_16x16x32_bf16(af, ones, accz[rt], 0, 0, 0);
        }
    };

    bf16x8 bA[4], bB[4];
    f32x4 eaA, ebA, faA, fbA, eaB, ebB, faB, fbB;
    uint32_t wA[4], wB[4];
    LOAD(jb0, bA, eaA, ebA, faA, fbA, wA);
    for (int js = 0; js < steps - 2; js += 2) {
        LOAD(jb0 + (js + 1) * 32, bB, eaB, ebB, faB, fbB, wB);
        COMP(bA, eaA, ebA, faA, fbA, wA);
        LOAD(jb0 + (js + 2) * 32, bA, eaA, ebA, faA, fbA, wA);
        COMP(bB, eaB, ebB, faB, fbB, wB);
    }
    LOAD(jb0 + (steps - 1) * 32, bB, eaB, ebB, faB, fbB, wB);
    COMP(bA, eaA, ebA, faA, fbA, wA);
    COMP(bB, eaB, ebB, faB, fbB, wB);

    bf16_t* Hp = Hpart + (size_t)jz * NN * CT;
#pragma unroll
    for (int rt = 0; rt < 4; ++rt) {
#pragma unroll
        for (int dt = 0; dt < 4; ++dt)
#pragma unroll
            for (int r = 0; r < 4; ++r)
                Hp[(size_t)(rowb + rt * 16 + kg * 4 + r) * CT + cb + dt * 16 + lr] = (bf16_t)acc[rt][dt][r];
    }
    if (lr == 0 && (ZC > 1 || c == 0)) {
        int zi = jz * ZC + (ZC > 1 ? c : 0);
#pragma unroll
        for (int rt = 0; rt < 4; ++rt)
#pragma unroll
            for (int r = 0; r < 4; ++r)
                zpart[(size_t)zi * NN + rowb + rt * 16 + kg * 4 + r] = accz[rt][r];
    }
}

// ---- finalize layer 1: hcatb = bf16(ELU(sum H / sum Z)), 8 cols/thread
__global__ __launch_bounds__(256) void fin1_k(const bf16_t* __restrict__ Hpart,
                                              const float* __restrict__ zpart,
                                              bf16_t* __restrict__ hcatb) {
    int idx = blockIdx.x * 256 + threadIdx.x;   // < N*64
    int i = idx >> 6, col0 = (idx & 63) << 3, h = col0 >> 6;
    float Z = 0.f;
#pragma unroll
    for (int jz = 0; jz < 8; ++jz) Z += zpart[(size_t)(jz * 8 + h) * NN + i];
    float hs[8];
#pragma unroll
    for (int e = 0; e < 8; ++e) hs[e] = 0.f;
#pragma unroll
    for (int jz = 0; jz < 8; ++jz) {
        bf16x8 v = *(const bf16x8*)(Hpart + ((size_t)jz * NN + i) * 512 + col0);
#pragma unroll
        for (int e = 0; e < 8; ++e) hs[e] += (float)v[e];
    }
    float invZ = 1.0f / Z;
    bf16x8 o;
#pragma unroll
    for (int e = 0; e < 8; ++e) {
        float v = hs[e] * invZ;
        o[e] = (bf16_t)(v > 0.f ? v : expm1f(v));
    }
    *(bf16x8*)(hcatb + (size_t)i * 512 + col0) = o;
}

// ---- combine split-K gemm2 slices: VT2 (j-tiled) + g/E2/F2. block=128thr=1 row.
__global__ __launch_bounds__(128) void comb2_k(const float* __restrict__ Cp,
                                               const float* __restrict__ a1o,
                                               const float* __restrict__ a2o,
                                               bf16_t* __restrict__ VT2t,
                                               float* __restrict__ g1o,
                                               float* __restrict__ E2o,
                                               float* __restrict__ F2o) {
    int r = blockIdx.x, t = threadIdx.x;
    float w = 0.f;
#pragma unroll
    for (int z = 0; z < 4; ++z) w += Cp[((size_t)z * NN + r) * 128 + t];
    VT2t[(size_t)(r >> 5) * (128 * 32) + t * 32 + (r & 31)] = (bf16_t)w;
    float d1 = w * a1o[t], d2 = w * a2o[t];
#pragma unroll
    for (int o = 1; o < 64; o <<= 1) { d1 += __shfl_xor(d1, o); d2 += __shfl_xor(d2, o); }
    __shared__ float red[4];
    if ((t & 63) == 0) { red[(t >> 6) * 2 + 0] = d1; red[(t >> 6) * 2 + 1] = d2; }
    __syncthreads();
    if (t == 0) {
        float s1 = red[0] + red[2], s2 = red[1] + red[3];
        g1o[r] = exp2f(-0.8f * LOG2E * s1);
        E2o[r] = exp2f(LOG2E * s2);
        F2o[r] = exp2f(0.2f * LOG2E * s2);
    }
}

// ---- finalize layer 2: out fp32 = sum H / sum Z, 8 cols/thread
__global__ __launch_bounds__(256) void fin2_k(const bf16_t* __restrict__ Hpart,
                                              const float* __restrict__ zpart,
                                              float* __restrict__ out) {
    int idx = blockIdx.x * 256 + threadIdx.x;   // < N*16
    int i = idx >> 4, col0 = (idx & 15) << 3;
    float Z = 0.f;
#pragma unroll
    for (int jz = 0; jz < 16; ++jz) Z += zpart[(size_t)jz * NN + i];
    float hs[8];
#pragma unroll
    for (int e = 0; e < 8; ++e) hs[e] = 0.f;
#pragma unroll
    for (int jz = 0; jz < 16; ++jz) {
        bf16x8 v = *(const bf16x8*)(Hpart + ((size_t)jz * NN + i) * 128 + col0);
#pragma unroll
        for (int e = 0; e < 8; ++e) hs[e] += (float)v[e];
    }
    float invZ = 1.0f / Z;
    f32x4 o0, o1;
#pragma unroll
    for (int e = 0; e < 4; ++e) { o0[e] = hs[e] * invZ; o1[e] = hs[e + 4] * invZ; }
    *(f32x4*)(out + (size_t)i * 128 + col0) = o0;
    *(f32x4*)(out + (size_t)i * 128 + col0 + 4) = o1;
}

extern "C" void kernel_launch(void* const* d_in, const int* in_sizes, int n_in,
                              void* d_out, int out_size, void* d_ws, size_t ws_size,
                              hipStream_t stream) {
    const int N = 4096;
    const float* x       = (const float*)d_in[0];
    const int*   adj     = (const int*)d_in[1];
    const float* W_heads = (const float*)d_in[2];
    const float* a1h     = (const float*)d_in[3];
    const float* a2h     = (const float*)d_in[4];
    const float* W_out   = (const float*)d_in[5];
    const float* a1o     = (const float*)d_in[6];
    const float* a2o     = (const float*)d_in[7];
    (void)in_sizes; (void)n_in; (void)out_size; (void)ws_size;

    size_t off = 0;
    auto alloc = [&](size_t bytes) { size_t o = off; off = (off + bytes + 255) & ~(size_t)255; return o; };
    char* ws = (char*)d_ws;
    uint32_t* bitsT = (uint32_t*)(ws + alloc((size_t)N * N / 8));        // 2 MB
    bf16_t* VT1t    = (bf16_t*)(ws + alloc((size_t)512 * N * 2));        // 4 MB (j-tiled)
    bf16_t* hcatb   = (bf16_t*)(ws + alloc((size_t)N * 512 * 2));        // 4 MB
    bf16_t* WoutT   = (bf16_t*)(ws + alloc((size_t)128 * 512 * 2));      // 128 KB
    float*  g1h     = (float*)(ws + alloc((size_t)8 * N * 4));
    float*  E2h     = (float*)(ws + alloc((size_t)8 * N * 4));
    float*  F2h     = (float*)(ws + alloc((size_t)8 * N * 4));
    float*  g1o     = (float*)(ws + alloc((size_t)N * 4));
    float*  E2o     = (float*)(ws + alloc((size_t)N * 4));
    float*  F2o     = (float*)(ws + alloc((size_t)N * 4));
    bf16_t* VT2t    = (bf16_t*)(ws + alloc((size_t)128 * N * 2));        // 1 MB (j-tiled)
    float*  zpart   = (float*)(ws + alloc((size_t)64 * N * 4));          // 1 MB
    bf16_t* Hpart   = (bf16_t*)(ws + alloc((size_t)32 * 1024 * 1024));   // 32 MB
    // aliases into the Hpart region (temporally disjoint):
    bf16_t* xbt   = (bf16_t*)Hpart;                       // 4 MB, dead after gemm1
    bf16_t* WT1t  = (bf16_t*)((char*)Hpart + (9 << 20));  // 0.5 MB, dead after gemm1
    float*  Cpart = (float*)Hpart;                        // gemm2..comb2 only

    // 1. adjacency bitmask (transposed)
    hipLaunchKernelGGL(pack_bits_k, dim3(2048), dim3(256), 0, stream, adj, bitsT, N * N);
    // 2. prep: K-tiled bf16 xbt/WT1t + row-major WoutT
    hipLaunchKernelGGL(prep_k, dim3(1024), dim3(256), 0, stream, x, W_heads, W_out, xbt, WT1t, WoutT);
    // 3. gemm1 (TILED inputs): VT1t + g/E2/F2 per head
    hipLaunchKernelGGL((gemm_k<1, 0, 1>), dim3(64, 8, 1), dim3(256), 0, stream,
                       xbt, WT1t, VT1t, (float*)nullptr, a1h, a2h, g1h, E2h, F2h, 512, 512, 512, 512);
    // 4. layer-1 aggregate: grid x=(head,jzgrp)=16, y=rowtile=64; jz = jzgrp*4+wave
    hipLaunchKernelGGL((gat_agg_k<2>), dim3(16, 64, 1), dim3(256), 0, stream,
                       g1h, E2h, F2h, N, bitsT, VT1t, Hpart, zpart, 512, 512, 8, 512 * 32);
    // 5. finalize 1 -> hcatb
    hipLaunchKernelGGL(fin1_k, dim3(1024), dim3(256), 0, stream, Hpart, zpart, hcatb);
    // 6. gemm2 split-K=4 (row-major inputs) -> Cpart
    hipLaunchKernelGGL((gemm_k<0, 1, 0>), dim3(64, 2, 4), dim3(256), 0, stream,
                       hcatb, WoutT, (bf16_t*)nullptr, Cpart,
                       (const float*)nullptr, (const float*)nullptr,
                       (float*)nullptr, (float*)nullptr, (float*)nullptr, 512, 128, 128, 128);
    // 7. combine -> VT2 tiled, g1o/E2o/F2o
    hipLaunchKernelGGL(comb2_k, dim3(4096), dim3(128), 0, stream, Cpart, a1o, a2o, VT2t, g1o, E2o, F2o);
    // 8. layer-2 aggregate: grid x=(c,jzgrp)=8, y=rowtile=64; jz = jzgrp*4+wave
    hipLaunchKernelGGL((gat_agg_k<4>), dim3(8, 64, 1), dim3(256), 0, stream,
                       g1o, E2o, F2o, 0, bitsT, VT2t, Hpart, zpart, 128, 256, 1, 128 * 32);
    // 9. finalize 2 -> out
    hipLaunchKernelGGL(fin2_k, dim3(256), dim3(256), 0, stream, Hpart, zpart, (float*)d_out);
}

// Round 14
// 136.494 us; speedup vs baseline: 1.1111x; 1.0225x over previous
//
#include <hip/hip_runtime.h>
#include <hip/hip_bf16.h>
#include <cstdint>

// ---------------------------------------------------------------------------
// GAT forward, N=4096, F=512, D=64, H=8, O=128, fp32 in/out.
// Identity: exp(lrelu(u)) = max(exp(u), exp(0.2u)); u = s1_i+s2_j rank-1;
// softmax row-scale invariance => p'_ij = max(E2_j, g_i*F2_j), g=exp(-0.8 s1).
// Round-14 = Round-13 (proven 139.6us) + two changes:
//   (1) V stored f16 (VT1t/VT2t), agg uses mfma_f32_16x16x32_f16 with
//       f16-converted P. E2/F2/masking/gemm-MFMA unchanged (bisects the
//       R11 f16 bug: pass -> bug was packed-math/f16-factors side).
//   (2) layer-1 jz split 8 -> 4: Hpart 16MB, fin1 reads halved, agg1
//       per-wave steps 16 -> 32 (prologue amortization).
// ---------------------------------------------------------------------------

using bf16_t = __bf16;
using half_t = _Float16;
using bf16x4 = __attribute__((ext_vector_type(4))) __bf16;
using bf16x8 = __attribute__((ext_vector_type(8))) __bf16;
using f16x4  = __attribute__((ext_vector_type(4))) _Float16;
using f16x8  = __attribute__((ext_vector_type(8))) _Float16;
using f32x4  = __attribute__((ext_vector_type(4))) float;

#define LOG2E 1.44269504f
constexpr int NN = 4096;

// ---- pack adjacency into TRANSPOSED bitmask: bitsT[(j>>5)*N + i], bit j&31
__global__ __launch_bounds__(256) void pack_bits_k(const int* __restrict__ adj,
                                                   uint32_t* __restrict__ bitsT, int total) {
    int stride = gridDim.x * blockDim.x;
    for (int idx = blockIdx.x * blockDim.x + threadIdx.x; idx < total; idx += stride) {
        unsigned long long m = __ballot(adj[idx] > 0);
        int l = threadIdx.x & 63;
        int i = idx >> 12, j = idx & 4095;
        if (l == 0)        bitsT[(size_t)(j >> 5) * NN + i] = (uint32_t)m;
        else if (l == 32)  bitsT[(size_t)(j >> 5) * NN + i] = (uint32_t)(m >> 32);
    }
}

// ---- prep: x -> xbt (K-tiled bf16 [kc][4096][32]),
//            W_heads -> WT1t ([kc][512][32]), W_out -> WoutT[o][512] row-major
__global__ __launch_bounds__(256) void prep_k(const float* __restrict__ x,
                                              const float* __restrict__ Wh,
                                              const float* __restrict__ Wo,
                                              bf16_t* __restrict__ xbt,
                                              bf16_t* __restrict__ WT1t,
                                              bf16_t* __restrict__ WoutT) {
    const int NXT = NN * 512 / 8;
    const int NWT = 512 * 512 / 8;
    const int NW2 = 128 * 512;
    int stride = gridDim.x * blockDim.x;
    for (int t = blockIdx.x * blockDim.x + threadIdx.x; t < NXT + NWT + NW2; t += stride) {
        if (t < NXT) {
            size_t d = (size_t)t * 8;
            int kc = (int)(d >> 17);
            int rem = (int)(d & 131071);
            int i = rem >> 5, k0 = rem & 31;
            const float* sp = x + (size_t)i * 512 + kc * 32 + k0;
            f32x4 s0 = *(const f32x4*)sp;
            f32x4 s1 = *(const f32x4*)(sp + 4);
            bf16x8 o;
#pragma unroll
            for (int e = 0; e < 4; ++e) { o[e] = (bf16_t)s0[e]; o[4 + e] = (bf16_t)s1[e]; }
            *(bf16x8*)(xbt + d) = o;
        } else if (t < NXT + NWT) {
            size_t d = (size_t)(t - NXT) * 8;
            int kc = (int)(d >> 14);
            int rem = (int)(d & 16383);
            int col = rem >> 5, k0 = rem & 31;
            int h = col >> 6, dd = col & 63;
            bf16x8 o;
#pragma unroll
            for (int e = 0; e < 8; ++e)
                o[e] = (bf16_t)Wh[(size_t)(h << 15) + (size_t)(kc * 32 + k0 + e) * 64 + dd];
            *(bf16x8*)(WT1t + d) = o;
        } else {
            int u = t - NXT - NWT;
            int o2 = u >> 9, cc = u & 511;
            WoutT[u] = (bf16_t)Wo[cc * 128 + o2];
        }
    }
}

// ---- bf16 MFMA GEMM, 4 waves/block, wave = 16 rows x 64 cols.
// TILED=1: A/B read K-tiled [kc][row|col][32]; TILED=0: row-major (gemm2).
// CS: epilogue writes VTt as F16 (j-tiled [i>>5][col][i&31]) + g/E2/F2.
// WC: writes fp32 partial C slice (split-K via blockIdx.z)
template<int CS, int WC, int TILED>
__global__ __launch_bounds__(256) void gemm_k(const bf16_t* __restrict__ A,
                                              const bf16_t* __restrict__ BT,
                                              half_t* __restrict__ VTt,
                                              float* __restrict__ Cp,
                                              const float* __restrict__ a1,
                                              const float* __restrict__ a2,
                                              float* __restrict__ g1,
                                              float* __restrict__ E2,
                                              float* __restrict__ F2,
                                              int K, int NC, int kslice, int NCOLS) {
    const int wave = threadIdx.x >> 6, lane = threadIdx.x & 63;
    const int lr = lane & 15, kg = lane >> 4;
    const int rowb = (blockIdx.x * 4 + wave) * 16, cb = blockIdx.y * 64, kz = blockIdx.z;
    f32x4 acc[4];
#pragma unroll
    for (int dt = 0; dt < 4; ++dt) acc[dt] = 0.0f;
    const int k0beg = kz * kslice, k0end = k0beg + kslice;
    for (int k0 = k0beg; k0 < k0end; k0 += 32) {
        bf16x8 af;
        if (TILED) {
            const int kc = k0 >> 5;
            af = *(const bf16x8*)(A + (size_t)kc * (NN * 32) + (size_t)(rowb + lr) * 32 + kg * 8);
        } else {
            af = *(const bf16x8*)(A + (size_t)(rowb + lr) * K + k0 + kg * 8);
        }
#pragma unroll
        for (int dt = 0; dt < 4; ++dt) {
            bf16x8 bfr;
            if (TILED) {
                const int kc = k0 >> 5;
                bfr = *(const bf16x8*)(BT + (size_t)kc * (NC * 32) +
                                       (size_t)(cb + dt * 16 + lr) * 32 + kg * 8);
            } else {
                bfr = *(const bf16x8*)(BT + (size_t)(cb + dt * 16 + lr) * K + k0 + kg * 8);
            }
            acc[dt] = __builtin_amdgcn_mfma_f32_16x16x32_bf16(af, bfr, acc[dt], 0, 0, 0);
        }
    }
    if (WC) {
#pragma unroll
        for (int dt = 0; dt < 4; ++dt)
#pragma unroll
            for (int r = 0; r < 4; ++r)
                Cp[((size_t)kz * NN + rowb + kg * 4 + r) * NC + cb + dt * 16 + lr] = acc[dt][r];
    }
    if (CS) {
        const int i0 = rowb + kg * 4;
        const size_t tbase = (size_t)(i0 >> 5) * NCOLS * 32 + (i0 & 31);
#pragma unroll
        for (int dt = 0; dt < 4; ++dt) {
            f16x4 v;
#pragma unroll
            for (int r = 0; r < 4; ++r) v[r] = (half_t)acc[dt][r];
            *(f16x4*)(VTt + tbase + (size_t)(cb + dt * 16 + lr) * 32) = v;
        }
        float a1v[4], a2v[4];
#pragma unroll
        for (int dt = 0; dt < 4; ++dt) {
            a1v[dt] = a1[cb + dt * 16 + lr];
            a2v[dt] = a2[cb + dt * 16 + lr];
        }
#pragma unroll
        for (int r = 0; r < 4; ++r) {
            float d1 = 0.f, d2 = 0.f;
#pragma unroll
            for (int dt = 0; dt < 4; ++dt) { d1 += acc[dt][r] * a1v[dt]; d2 += acc[dt][r] * a2v[dt]; }
#pragma unroll
            for (int o = 1; o < 16; o <<= 1) { d1 += __shfl_xor(d1, o); d2 += __shfl_xor(d2, o); }
            if (lr == 0) {
                size_t row = (size_t)blockIdx.y * NN + rowb + kg * 4 + r;
                g1[row] = exp2f(-0.8f * LOG2E * d1);
                E2[row] = exp2f(LOG2E * d2);
                F2[row] = exp2f(0.2f * LOG2E * d2);
            }
        }
    }
}

// ---- fused attention-aggregate (R13 structure, f16 V + f16 MFMA).
// grid = (CG*JZG, 64); x -> (c = x/JZG, jzgrp = x%JZG); y = rowtile.
// 4 waves/block; wave w owns jz = jzgrp*4 + w; wave = 64 rows x 64 cols.
// p'_ij = adj ? max(E2_j, g_i*F2_j) : 0  (f32 math, cvt f16, cndmask mask).
// Z row-sums via extra f16 MFMA against a ones-column B-fragment.
template<int JZG>
__global__ __launch_bounds__(256) void gat_agg_k(const float* __restrict__ g1,
                                                 const float* __restrict__ E2,
                                                 const float* __restrict__ F2, int shead,
                                                 const uint32_t* __restrict__ bitsT,
                                                 const half_t* __restrict__ VTt,
                                                 bf16_t* __restrict__ Hpart,
                                                 float* __restrict__ zpart,
                                                 int CT, int JR, int ZC, int TS) {
    const int wave = threadIdx.x >> 6, lane = threadIdx.x & 63;
    const int lr = lane & 15, kg = lane >> 4;
    const int c = blockIdx.x / JZG, jzg = blockIdx.x % JZG;
    const int rowb = blockIdx.y * 64;
    const int jz = jzg * 4 + wave;
    const int cb = c * 64;
    const float* gp  = g1 + (size_t)shead * c;
    const float* E2p = E2 + (size_t)shead * c;
    const float* F2p = F2 + (size_t)shead * c;
    const int steps = JR >> 5, jb0 = jz * JR;

    f32x4 acc[4][4], accz[4];
#pragma unroll
    for (int rt = 0; rt < 4; ++rt) {
        accz[rt] = 0.0f;
#pragma unroll
        for (int dt = 0; dt < 4; ++dt) acc[rt][dt] = 0.0f;
    }
    float gv[4];
#pragma unroll
    for (int rt = 0; rt < 4; ++rt) gv[rt] = gp[rowb + rt * 16 + lr];
    f16x8 ones;
#pragma unroll
    for (int e = 0; e < 8; ++e) ones[e] = (half_t)(lr == 0 ? 1.0f : 0.0f);

    auto LOAD = [&](int jb, f16x8* bfr, f32x4& e2a, f32x4& e2b, f32x4& f2a, f32x4& f2b,
                    uint32_t* bw) {
        const int jk = jb + kg * 8;
        const int jc = jb >> 5;
        e2a = *(const f32x4*)(E2p + jk);
        e2b = *(const f32x4*)(E2p + jk + 4);
        f2a = *(const f32x4*)(F2p + jk);
        f2b = *(const f32x4*)(F2p + jk + 4);
        const half_t* vb = VTt + (size_t)jc * TS + kg * 8;
#pragma unroll
        for (int dt = 0; dt < 4; ++dt)
            bfr[dt] = *(const f16x8*)(vb + (size_t)(cb + dt * 16 + lr) * 32);
        const uint32_t* bb = bitsT + (size_t)jc * NN + rowb;
#pragma unroll
        for (int rt = 0; rt < 4; ++rt)
            bw[rt] = bb[rt * 16 + lr];
    };
    auto COMP = [&](const f16x8* bfr, f32x4 e2a, f32x4 e2b, f32x4 f2a, f32x4 f2b,
                    const uint32_t* bw) {
#pragma unroll
        for (int rt = 0; rt < 4; ++rt) {
            uint32_t mb = (bw[rt] >> (kg * 8)) & 0xffu;
            f16x8 af;
#pragma unroll
            for (int e = 0; e < 8; ++e) {
                float e2 = (e < 4) ? e2a[e] : e2b[e - 4];
                float f2 = (e < 4) ? f2a[e] : f2b[e - 4];
                float p = fmaxf(e2, gv[rt] * f2);
                p = (mb & (1u << e)) ? p : 0.0f;
                af[e] = (half_t)p;
            }
#pragma unroll
            for (int dt = 0; dt < 4; ++dt)
                acc[rt][dt] = __builtin_amdgcn_mfma_f32_16x16x32_f16(af, bfr[dt], acc[rt][dt], 0, 0, 0);
            accz[rt] = __builtin_amdgcn_mfma_f32_16x16x32_f16(af, ones, accz[rt], 0, 0, 0);
        }
    };

    f16x8 bA[4], bB[4];
    f32x4 eaA, ebA, faA, fbA, eaB, ebB, faB, fbB;
    uint32_t wA[4], wB[4];
    LOAD(jb0, bA, eaA, ebA, faA, fbA, wA);
    for (int js = 0; js < steps - 2; js += 2) {
        LOAD(jb0 + (js + 1) * 32, bB, eaB, ebB, faB, fbB, wB);
        COMP(bA, eaA, ebA, faA, fbA, wA);
        LOAD(jb0 + (js + 2) * 32, bA, eaA, ebA, faA, fbA, wA);
        COMP(bB, eaB, ebB, faB, fbB, wB);
    }
    LOAD(jb0 + (steps - 1) * 32, bB, eaB, ebB, faB, fbB, wB);
    COMP(bA, eaA, ebA, faA, fbA, wA);
    COMP(bB, eaB, ebB, faB, fbB, wB);

    bf16_t* Hp = Hpart + (size_t)jz * NN * CT;
#pragma unroll
    for (int rt = 0; rt < 4; ++rt) {
#pragma unroll
        for (int dt = 0; dt < 4; ++dt)
#pragma unroll
            for (int r = 0; r < 4; ++r)
                Hp[(size_t)(rowb + rt * 16 + kg * 4 + r) * CT + cb + dt * 16 + lr] = (bf16_t)acc[rt][dt][r];
    }
    if (lr == 0 && (ZC > 1 || c == 0)) {
        int zi = jz * ZC + (ZC > 1 ? c : 0);
#pragma unroll
        for (int rt = 0; rt < 4; ++rt)
#pragma unroll
            for (int r = 0; r < 4; ++r)
                zpart[(size_t)zi * NN + rowb + rt * 16 + kg * 4 + r] = accz[rt][r];
    }
}

// ---- finalize layer 1: hcatb = bf16(ELU(sum H / sum Z)), 8 cols/thread
__global__ __launch_bounds__(256) void fin1_k(const bf16_t* __restrict__ Hpart,
                                              const float* __restrict__ zpart,
                                              bf16_t* __restrict__ hcatb) {
    int idx = blockIdx.x * 256 + threadIdx.x;   // < N*64
    int i = idx >> 6, col0 = (idx & 63) << 3, h = col0 >> 6;
    float Z = 0.f;
#pragma unroll
    for (int jz = 0; jz < 4; ++jz) Z += zpart[(size_t)(jz * 8 + h) * NN + i];
    float hs[8];
#pragma unroll
    for (int e = 0; e < 8; ++e) hs[e] = 0.f;
#pragma unroll
    for (int jz = 0; jz < 4; ++jz) {
        bf16x8 v = *(const bf16x8*)(Hpart + ((size_t)jz * NN + i) * 512 + col0);
#pragma unroll
        for (int e = 0; e < 8; ++e) hs[e] += (float)v[e];
    }
    float invZ = 1.0f / Z;
    bf16x8 o;
#pragma unroll
    for (int e = 0; e < 8; ++e) {
        float v = hs[e] * invZ;
        o[e] = (bf16_t)(v > 0.f ? v : expm1f(v));
    }
    *(bf16x8*)(hcatb + (size_t)i * 512 + col0) = o;
}

// ---- combine split-K gemm2 slices: VT2t (j-tiled f16) + g/E2/F2. 128thr=1 row.
__global__ __launch_bounds__(128) void comb2_k(const float* __restrict__ Cp,
                                               const float* __restrict__ a1o,
                                               const float* __restrict__ a2o,
                                               half_t* __restrict__ VT2t,
                                               float* __restrict__ g1o,
                                               float* __restrict__ E2o,
                                               float* __restrict__ F2o) {
    int r = blockIdx.x, t = threadIdx.x;
    float w = 0.f;
#pragma unroll
    for (int z = 0; z < 4; ++z) w += Cp[((size_t)z * NN + r) * 128 + t];
    VT2t[(size_t)(r >> 5) * (128 * 32) + t * 32 + (r & 31)] = (half_t)w;
    float d1 = w * a1o[t], d2 = w * a2o[t];
#pragma unroll
    for (int o = 1; o < 64; o <<= 1) { d1 += __shfl_xor(d1, o); d2 += __shfl_xor(d2, o); }
    __shared__ float red[4];
    if ((t & 63) == 0) { red[(t >> 6) * 2 + 0] = d1; red[(t >> 6) * 2 + 1] = d2; }
    __syncthreads();
    if (t == 0) {
        float s1 = red[0] + red[2], s2 = red[1] + red[3];
        g1o[r] = exp2f(-0.8f * LOG2E * s1);
        E2o[r] = exp2f(LOG2E * s2);
        F2o[r] = exp2f(0.2f * LOG2E * s2);
    }
}

// ---- finalize layer 2: out fp32 = sum H / sum Z, 8 cols/thread
__global__ __launch_bounds__(256) void fin2_k(const bf16_t* __restrict__ Hpart,
                                              const float* __restrict__ zpart,
                                              float* __restrict__ out) {
    int idx = blockIdx.x * 256 + threadIdx.x;   // < N*16
    int i = idx >> 4, col0 = (idx & 15) << 3;
    float Z = 0.f;
#pragma unroll
    for (int jz = 0; jz < 16; ++jz) Z += zpart[(size_t)jz * NN + i];
    float hs[8];
#pragma unroll
    for (int e = 0; e < 8; ++e) hs[e] = 0.f;
#pragma unroll
    for (int jz = 0; jz < 16; ++jz) {
        bf16x8 v = *(const bf16x8*)(Hpart + ((size_t)jz * NN + i) * 128 + col0);
#pragma unroll
        for (int e = 0; e < 8; ++e) hs[e] += (float)v[e];
    }
    float invZ = 1.0f / Z;
    f32x4 o0, o1;
#pragma unroll
    for (int e = 0; e < 4; ++e) { o0[e] = hs[e] * invZ; o1[e] = hs[e + 4] * invZ; }
    *(f32x4*)(out + (size_t)i * 128 + col0) = o0;
    *(f32x4*)(out + (size_t)i * 128 + col0 + 4) = o1;
}

extern "C" void kernel_launch(void* const* d_in, const int* in_sizes, int n_in,
                              void* d_out, int out_size, void* d_ws, size_t ws_size,
                              hipStream_t stream) {
    const int N = 4096;
    const float* x       = (const float*)d_in[0];
    const int*   adj     = (const int*)d_in[1];
    const float* W_heads = (const float*)d_in[2];
    const float* a1h     = (const float*)d_in[3];
    const float* a2h     = (const float*)d_in[4];
    const float* W_out   = (const float*)d_in[5];
    const float* a1o     = (const float*)d_in[6];
    const float* a2o     = (const float*)d_in[7];
    (void)in_sizes; (void)n_in; (void)out_size; (void)ws_size;

    size_t off = 0;
    auto alloc = [&](size_t bytes) { size_t o = off; off = (off + bytes + 255) & ~(size_t)255; return o; };
    char* ws = (char*)d_ws;
    uint32_t* bitsT = (uint32_t*)(ws + alloc((size_t)N * N / 8));        // 2 MB
    half_t* VT1t    = (half_t*)(ws + alloc((size_t)512 * N * 2));        // 4 MB (j-tiled f16)
    bf16_t* hcatb   = (bf16_t*)(ws + alloc((size_t)N * 512 * 2));        // 4 MB
    bf16_t* WoutT   = (bf16_t*)(ws + alloc((size_t)128 * 512 * 2));      // 128 KB
    float*  g1h     = (float*)(ws + alloc((size_t)8 * N * 4));
    float*  E2h     = (float*)(ws + alloc((size_t)8 * N * 4));
    float*  F2h     = (float*)(ws + alloc((size_t)8 * N * 4));
    float*  g1o     = (float*)(ws + alloc((size_t)N * 4));
    float*  E2o     = (float*)(ws + alloc((size_t)N * 4));
    float*  F2o     = (float*)(ws + alloc((size_t)N * 4));
    half_t* VT2t    = (half_t*)(ws + alloc((size_t)128 * N * 2));        // 1 MB (j-tiled f16)
    float*  zpart   = (float*)(ws + alloc((size_t)64 * N * 4));          // 1 MB
    bf16_t* Hpart   = (bf16_t*)(ws + alloc((size_t)32 * 1024 * 1024));   // 32 MB (16 used L1)
    // aliases into the Hpart region (temporally disjoint):
    bf16_t* xbt   = (bf16_t*)Hpart;                       // 4 MB, dead after gemm1
    bf16_t* WT1t  = (bf16_t*)((char*)Hpart + (9 << 20));  // 0.5 MB, dead after gemm1
    float*  Cpart = (float*)Hpart;                        // gemm2..comb2 only

    // 1. adjacency bitmask (transposed)
    hipLaunchKernelGGL(pack_bits_k, dim3(2048), dim3(256), 0, stream, adj, bitsT, N * N);
    // 2. prep: K-tiled bf16 xbt/WT1t + row-major WoutT
    hipLaunchKernelGGL(prep_k, dim3(1024), dim3(256), 0, stream, x, W_heads, W_out, xbt, WT1t, WoutT);
    // 3. gemm1 (TILED inputs): VT1t (f16) + g/E2/F2 per head
    hipLaunchKernelGGL((gemm_k<1, 0, 1>), dim3(64, 8, 1), dim3(256), 0, stream,
                       xbt, WT1t, VT1t, (float*)nullptr, a1h, a2h, g1h, E2h, F2h, 512, 512, 512, 512);
    // 4. layer-1 aggregate: grid x=head(8), y=rowtile(64); jz = wave (0..3), JR=1024
    hipLaunchKernelGGL((gat_agg_k<1>), dim3(8, 64, 1), dim3(256), 0, stream,
                       g1h, E2h, F2h, N, bitsT, VT1t, Hpart, zpart, 512, 1024, 8, 512 * 32);
    // 5. finalize 1 -> hcatb
    hipLaunchKernelGGL(fin1_k, dim3(1024), dim3(256), 0, stream, Hpart, zpart, hcatb);
    // 6. gemm2 split-K=4 (row-major inputs) -> Cpart
    hipLaunchKernelGGL((gemm_k<0, 1, 0>), dim3(64, 2, 4), dim3(256), 0, stream,
                       hcatb, WoutT, (half_t*)nullptr, Cpart,
                       (const float*)nullptr, (const float*)nullptr,
                       (float*)nullptr, (float*)nullptr, (float*)nullptr, 512, 128, 128, 128);
    // 7. combine -> VT2t (f16), g1o/E2o/F2o
    hipLaunchKernelGGL(comb2_k, dim3(4096), dim3(128), 0, stream, Cpart, a1o, a2o, VT2t, g1o, E2o, F2o);
    // 8. layer-2 aggregate: grid x=(c,jzgrp)=8, y=rowtile=64; jz = jzgrp*4+wave
    hipLaunchKernelGGL((gat_agg_k<4>), dim3(8, 64, 1), dim3(256), 0, stream,
                       g1o, E2o, F2o, 0, bitsT, VT2t, Hpart, zpart, 128, 256, 1, 128 * 32);
    // 9. finalize 2 -> out
    hipLaunchKernelGGL(fin2_k, dim3(256), dim3(256), 0, stream, Hpart, zpart, (float*)d_out);
}